// Round 9
// baseline (274.767 us; speedup 1.0000x reference)
//
#include <hip/hip_runtime.h>
#include <hip/hip_bf16.h>

#define B_    1024
#define NHID_ 4096
#define NBO   8
#define BSO   512
#define DK_   64

typedef __bf16 bf16;
typedef __bf16 bf16x2 __attribute__((ext_vector_type(2)));
typedef __bf16 bf16x4 __attribute__((ext_vector_type(4)));
typedef __bf16 bf16x8 __attribute__((ext_vector_type(8)));
typedef float  f32x4  __attribute__((ext_vector_type(4)));

__device__ __forceinline__ float sigf(float x){
    float e = __expf(-x);
    return __builtin_amdgcn_rcpf(1.0f + e);
}
__device__ __forceinline__ float ftanh(float x){
    float e = __expf(2.0f*x);
    return 1.0f - 2.0f*__builtin_amdgcn_rcpf(e + 1.0f);
}

// async global->LDS, 16B per lane; lds dest is wave-uniform base (+lane*16 implicit)
__device__ __forceinline__ void gload16(const void* g, void* lds){
    __builtin_amdgcn_global_load_lds((const __attribute__((address_space(1))) unsigned int*)g,
                                     (__attribute__((address_space(3))) unsigned int*)lds,
                                     16, 0, 0);
}

// raw barrier without the compiler's vmcnt(0) drain; empty asm pins memory ops
__device__ __forceinline__ void sbar(){
    asm volatile("" ::: "memory");
    __builtin_amdgcn_s_barrier();
    asm volatile("" ::: "memory");
}
#define WAITVM(N) asm volatile("s_waitcnt vmcnt(" #N ")" ::: "memory")

// ---------------------------------------------------------------- merged prep + qkv (v2):
// bid < 768:      input-attn q/k/v GEMMs (fp32 exact, K-split z)
// next 4096:      w_ih/w_hh -> bf16 transposed wT[n][gcol2048][k1024]
// next 4096:      hx -> bf16
// next 192:       mha qkv weight tile-transpose (coalesced; was stride-256B scalar)
// next 8:         ia_fc tile-transpose
// next 16:        fc|gate paired tile-transpose
__global__ __launch_bounds__(256) void k_prepqkv(
    const float* __restrict__ w_ih, const float* __restrict__ w_hh,
    const float* __restrict__ hx, const float* __restrict__ inp,
    const float* __restrict__ ia_wq, const float* __restrict__ ia_wk,
    const float* __restrict__ ia_wv,
    const float* __restrict__ mha_wq, const float* __restrict__ mha_wk,
    const float* __restrict__ mha_wv, const float* __restrict__ ia_fc_w,
    const float* __restrict__ fc_w, const float* __restrict__ gate_w,
    bf16* __restrict__ wT, bf16* __restrict__ hb16, bf16* __restrict__ wqkvT,
    bf16* __restrict__ iafcT, bf16* __restrict__ fcgT,
    float* __restrict__ qbufH, float* __restrict__ kbufH, float* __restrict__ vbufH)
{
    int bid = blockIdx.x;
    int t = threadIdx.x;
    __shared__ float Af[32][36];
    __shared__ float W1[32][68];
    __shared__ float W2[32][68];
    __shared__ float tile[64][65];

    if (bid < 768){
        int z = (bid >= 384) ? 1 : 0;
        int r = bid - z*384;
        int y = r >> 5, b0 = (r & 31)*32;
        int tx = t&15, ty = t>>4;
        if (y < 8){
            int n = y;
            float acc[2][4] = {};
            for (int k0=z*256; k0<z*256+256; k0+=32){
                { int row=t>>3, c4=(t&7)*4;
                  *(float4*)&Af[row][c4] = *(const float4*)&hx[(size_t)(b0+row)*4096 + n*512 + k0 + c4]; }
                #pragma unroll
                for (int j=0;j<2;++j){
                    int id = j*256 + t;
                    int kk = id>>4, e4 = (id&15)*4;
                    *(float4*)&W1[kk][e4] = *(const float4*)&ia_wq[(size_t)n*32768 + (size_t)(k0+kk)*64 + e4];
                }
                __syncthreads();
                #pragma unroll
                for (int kk4=0; kk4<8; ++kk4){
                    float4 a0 = *(float4*)&Af[ty*2  ][kk4*4];
                    float4 a1 = *(float4*)&Af[ty*2+1][kk4*4];
                    #pragma unroll
                    for (int j=0;j<4;++j){
                        float4 wv = *(float4*)&W1[kk4*4+j][tx*4];
                        float s0 = (j==0)?a0.x:((j==1)?a0.y:((j==2)?a0.z:a0.w));
                        float s1 = (j==0)?a1.x:((j==1)?a1.y:((j==2)?a1.z:a1.w));
                        acc[0][0]+=s0*wv.x; acc[0][1]+=s0*wv.y; acc[0][2]+=s0*wv.z; acc[0][3]+=s0*wv.w;
                        acc[1][0]+=s1*wv.x; acc[1][1]+=s1*wv.y; acc[1][2]+=s1*wv.z; acc[1][3]+=s1*wv.w;
                    }
                }
                __syncthreads();
            }
            #pragma unroll
            for (int r2=0;r2<2;++r2){
                float4 o; o.x=acc[r2][0]; o.y=acc[r2][1]; o.z=acc[r2][2]; o.w=acc[r2][3];
                *(float4*)&qbufH[((size_t)(z*B_ + b0+ty*2+r2))*512 + n*64 + tx*4] = o;
            }
        } else {
            int jb = y-8;
            float ak[2][4] = {}, av[2][4] = {};
            for (int k0=z*64; k0<z*64+64; k0+=32){
                { int row=t>>3, c4=(t&7)*4;
                  *(float4*)&Af[row][c4] = *(const float4*)&inp[(size_t)(b0+row)*512 + jb*128 + k0 + c4]; }
                #pragma unroll
                for (int j=0;j<2;++j){
                    int id = j*256 + t;
                    int kk = id>>4, e4 = (id&15)*4;
                    *(float4*)&W1[kk][e4] = *(const float4*)&ia_wk[(size_t)jb*8192 + (size_t)(k0+kk)*64 + e4];
                    *(float4*)&W2[kk][e4] = *(const float4*)&ia_wv[(size_t)jb*8192 + (size_t)(k0+kk)*64 + e4];
                }
                __syncthreads();
                #pragma unroll
                for (int kk4=0; kk4<8; ++kk4){
                    float4 a0 = *(float4*)&Af[ty*2  ][kk4*4];
                    float4 a1 = *(float4*)&Af[ty*2+1][kk4*4];
                    #pragma unroll
                    for (int j=0;j<4;++j){
                        float4 wk = *(float4*)&W1[kk4*4+j][tx*4];
                        float4 wv = *(float4*)&W2[kk4*4+j][tx*4];
                        float s0 = (j==0)?a0.x:((j==1)?a0.y:((j==2)?a0.z:a0.w));
                        float s1 = (j==0)?a1.x:((j==1)?a1.y:((j==2)?a1.z:a1.w));
                        ak[0][0]+=s0*wk.x; ak[0][1]+=s0*wk.y; ak[0][2]+=s0*wk.z; ak[0][3]+=s0*wk.w;
                        ak[1][0]+=s1*wk.x; ak[1][1]+=s1*wk.y; ak[1][2]+=s1*wk.z; ak[1][3]+=s1*wk.w;
                        av[0][0]+=s0*wv.x; av[0][1]+=s0*wv.y; av[0][2]+=s0*wv.z; av[0][3]+=s0*wv.w;
                        av[1][0]+=s1*wv.x; av[1][1]+=s1*wv.y; av[1][2]+=s1*wv.z; av[1][3]+=s1*wv.w;
                    }
                }
                __syncthreads();
            }
            #pragma unroll
            for (int r2=0;r2<2;++r2){
                float4 ok; ok.x=ak[r2][0]; ok.y=ak[r2][1]; ok.z=ak[r2][2]; ok.w=ak[r2][3];
                float4 ov; ov.x=av[r2][0]; ov.y=av[r2][1]; ov.z=av[r2][2]; ov.w=av[r2][3];
                *(float4*)&kbufH[((size_t)(z*B_ + b0+ty*2+r2))*256 + jb*64 + tx*4] = ok;
                *(float4*)&vbufH[((size_t)(z*B_ + b0+ty*2+r2))*256 + jb*64 + tx*4] = ov;
            }
        }
        return;
    }
    bid -= 768;
    if (bid < 4096){
        int c0 = (bid & 31)*64;
        int k0 = ((bid>>5)&7)*64;
        int z  = bid>>8;
        int n = z>>1, which = z&1;
        const float* src = (which ? w_hh : w_ih) + (size_t)n*512*2048;
        #pragma unroll
        for (int it=0; it<4; ++it){
            int idx = t + it*256;
            int r = idx>>4, c4 = (idx&15)*4;
            *(float4*)&tile[r][c4] = *(const float4*)&src[(size_t)(k0+r)*2048 + c0 + c4];
        }
        __syncthreads();
        #pragma unroll
        for (int it=0; it<2; ++it){
            int idx = t + it*256;
            int c = idx>>3, r8 = (idx&7)*8;
            bf16x8 v;
            #pragma unroll
            for (int jj=0;jj<8;++jj) v[jj] = (bf16)tile[r8+jj][c];
            *(bf16x8*)&wT[((size_t)n*2048 + c0 + c)*1024 + which*512 + k0 + r8] = v;
        }
        return;
    }
    bid -= 4096;
    if (bid < 4096){
        int gid = bid*256 + t;
        float4 v = ((const float4*)hx)[gid];
        bf16x4 o; o.x=(bf16)v.x; o.y=(bf16)v.y; o.z=(bf16)v.z; o.w=(bf16)v.w;
        *(bf16x4*)&hb16[(size_t)gid*4] = o;
        return;
    }
    bid -= 4096;
    if (bid < 192){   // wqkvT[(n*192 + p*64 + ee)*512 + k] = mha_wX[n][k][ee], 64k x 64ee tiles
        int kt = bid & 7, np = bid >> 3;
        int n = np / 3, p = np - n*3;
        int k0 = kt*64;
        const float* s = (p==0) ? mha_wq : ((p==1) ? mha_wk : mha_wv);
        #pragma unroll
        for (int it=0; it<4; ++it){
            int r = it*16 + (t>>4), c4 = (t&15)*4;
            *(float4*)&tile[r][c4] = *(const float4*)&s[((size_t)n*512 + k0 + r)*64 + c4];
        }
        __syncthreads();
        #pragma unroll
        for (int it=0; it<2; ++it){
            int idx = it*256 + t;
            int ee = idx>>3, k8 = (idx&7)*8;
            bf16x8 v;
            #pragma unroll
            for (int jj=0;jj<8;++jj) v[jj] = (bf16)tile[k8+jj][ee];
            *(bf16x8*)&wqkvT[((size_t)n*192 + p*64 + ee)*512 + k0 + k8] = v;
        }
        return;
    }
    bid -= 192;
    if (bid < 8){     // iafcT[c*64 + k] = ia_fc_w[k*512 + c], 64k x 64c tiles
        int c0 = bid*64;
        #pragma unroll
        for (int it=0; it<4; ++it){
            int k = it*16 + (t>>4), c4 = (t&15)*4;
            *(float4*)&tile[k][c4] = *(const float4*)&ia_fc_w[(size_t)k*512 + c0 + c4];
        }
        __syncthreads();
        #pragma unroll
        for (int it=0; it<2; ++it){
            int idx = it*256 + t;
            int cc = idx>>3, k8 = (idx&7)*8;
            bf16x8 v;
            #pragma unroll
            for (int jj=0;jj<8;++jj) v[jj] = (bf16)tile[k8+jj][cc];
            *(bf16x8*)&iafcT[(size_t)(c0+cc)*64 + k8] = v;
        }
        return;
    }
    bid -= 8;
    if (bid < 16){    // fcgT[(ct*64+j)*64 + k]: j<32 fc cols ct*32+j, j>=32 gate cols ct*32+j-32
        int ct = bid;
        #pragma unroll
        for (int it=0; it<4; ++it){
            int k = it*16 + (t>>4);
            int seg = t&15;
            int j4 = seg*4;
            const float* s = (seg < 8) ? &fc_w[(size_t)k*512 + ct*32 + j4]
                                       : &gate_w[(size_t)k*512 + ct*32 + (j4-32)];
            *(float4*)&tile[k][j4] = *(const float4*)s;
        }
        __syncthreads();
        #pragma unroll
        for (int it=0; it<2; ++it){
            int idx = it*256 + t;
            int j = idx>>3, k8 = (idx&7)*8;
            bf16x8 v;
            #pragma unroll
            for (int jj=0;jj<8;++jj) v[jj] = (bf16)tile[k8+jj][j];
            *(bf16x8*)&fcgT[(size_t)(ct*64 + j)*64 + k8] = v;
        }
    }
}

// ---------------------------------------------------------------- scores + softmax + top4 + o + fc_ia MFMA (fused)
// v4: 512 threads, 4 b per block (128 threads / 2 waves per b) -> 8 waves/CU (2/SIMD).
__global__ __launch_bounds__(512) void k_score(const float* __restrict__ qbufH,
                                               const float* __restrict__ kbufH,
                                               const float* __restrict__ vbufH,
                                               const bf16* __restrict__ iafcT,
                                               const float* __restrict__ ia_fc_b,
                                               bf16* __restrict__ xb16,
                                               float* __restrict__ maskb,
                                               float* __restrict__ mask_out)
{
    int t = threadIdx.x;
    int sb = t>>7, ts = t&127;           // b-group, thread-in-group
    int wv = (t>>6)&1, lw = t&63;        // wave-half of group, lane
    int b = blockIdx.x*4 + sb;
    __shared__ float q_s[4][512];
    __shared__ float k_s[4][256];
    __shared__ float v_s[4][256];
    __shared__ float at_s[4][40];
    __shared__ float sc_s[4][8];
    __shared__ float mb_s[4][8];
    __shared__ bf16 o_s[32][72];

    #pragma unroll
    for (int r=0;r<4;++r){
        int i = ts + r*128;
        q_s[sb][i] = qbufH[(size_t)b*512 + i] + qbufH[(size_t)(B_+b)*512 + i];
    }
    #pragma unroll
    for (int r=0;r<2;++r){
        int i = ts + r*128;
        k_s[sb][i] = kbufH[(size_t)b*256 + i] + kbufH[(size_t)(B_+b)*256 + i];
        v_s[sb][i] = vbufH[(size_t)b*256 + i] + vbufH[(size_t)(B_+b)*256 + i];
    }
    __syncthreads();
    {
        int n = wv*4 + (lw>>4);          // 4 n per wave
        int j = (lw>>2)&3;               // 4 j
        int ec = lw&3;                   // 4 e-chunks of 16
        const float* q = &q_s[sb][n*64 + ec*16];
        const float* k = &k_s[sb][j*64 + ec*16];
        float s = 0.f;
        #pragma unroll
        for (int e=0;e<16;++e) s += q[e]*k[e];
        s += __shfl_xor(s, 1);
        s += __shfl_xor(s, 2);
        if (ec==0) at_s[sb][n*5+j] = s*0.125f;
        if ((lw&15)==4) at_s[sb][n*5+4] = 0.f;
    }
    __syncthreads();
    if (lw < 4){                         // each wave: softmax for its 4 n's
        int n = wv*4 + lw;
        float m = at_s[sb][n*5];
        for (int j=1;j<5;++j) m = fmaxf(m, at_s[sb][n*5+j]);
        float ex[5]; float sum=0.f;
        for (int j=0;j<5;++j){ ex[j]=__expf(at_s[sb][n*5+j]-m); sum+=ex[j]; }
        float inv = 1.f/sum;
        for (int j=0;j<5;++j) at_s[sb][n*5+j] = ex[j]*inv;
        sc_s[sb][n] = ex[0]*inv;
    }
    __syncthreads();
    if (ts == 0){
        float s[8];
        for (int nn=0;nn<8;++nn) s[nn] = sc_s[sb][nn];
        for (int ii=1;ii<8;++ii){ float key=s[ii]; int jj=ii-1;
            while(jj>=0 && s[jj]<key){ s[jj+1]=s[jj]; --jj; } s[jj+1]=key; }
        float thr = s[3]-0.01f;
        for (int nn=0;nn<8;++nn) mb_s[sb][nn] = (sc_s[sb][nn] > thr) ? 1.0f : 0.0f;
    }
    __syncthreads();
    #pragma unroll
    for (int r=0;r<4;++r){
        int i = ts + r*128;
        int n = i>>6, e = i&63;
        float s = 0.f;
        #pragma unroll
        for (int j=0;j<4;++j) s += at_s[sb][n*5+j]*v_s[sb][j*64+e];
        o_s[sb*8+n][e] = (bf16)s;
    }
    if (ts < 8) maskb[b*8+ts] = mb_s[sb][ts];
    float4* mo = (float4*)(mask_out + (size_t)b*4096);
    #pragma unroll
    for (int r=0;r<8;++r){
        int i4 = ts + r*128;
        float m = mb_s[sb][i4>>7];
        float4 mv; mv.x=m; mv.y=m; mv.z=m; mv.w=m;
        mo[i4] = mv;
    }
    __syncthreads();
    // ---- fused fc_ia: M=32 (4b x 8n), N=512 over 8 waves (wd = 4 N-chunks), K=64 ----
    {
        int w = t>>6, l = t&63, quad = l>>4, l16 = l&15;
        int wm = w&1, wd = w>>1;         // wd 0..3
        bf16x8 a0 = *(const bf16x8*)&o_s[wm*16 + l16][quad*8];
        bf16x8 a1 = *(const bf16x8*)&o_s[wm*16 + l16][32 + quad*8];
        f32x4 zero = {0.f,0.f,0.f,0.f};
        #pragma unroll
        for (int nt=0; nt<8; ++nt){
            int cg = wd*128 + nt*16 + l16;
            bf16x8 b0 = *(const bf16x8*)&iafcT[(size_t)cg*64 + quad*8];
            bf16x8 b1 = *(const bf16x8*)&iafcT[(size_t)cg*64 + 32 + quad*8];
            f32x4 acc = __builtin_amdgcn_mfma_f32_16x16x32_bf16(a0, b0, zero, 0,0,0);
            acc = __builtin_amdgcn_mfma_f32_16x16x32_bf16(a1, b1, acc, 0,0,0);
            float bias = ia_fc_b[cg];
            #pragma unroll
            for (int v=0; v<4; ++v){
                int rm = wm*16 + quad*4 + v;
                int bb = blockIdx.x*4 + (rm>>3), nn = rm&7;
                xb16[(size_t)bb*4096 + nn*512 + cg] = (bf16)(acc[v] + bias);
            }
        }
    }
}

// ---------------------------------------------------------------- LSTM gates MFMA + pointwise (v7: v5 minus mid-tile barrier)
// 256x256 tile, 512 threads = 8 waves; BK=32, 4-deep LDS ring (128 KB).
// ONE barrier per K-tile; counted vmcnt(4); setprio around 32-MFMA cluster.
__global__ __launch_bounds__(512,2) void k_lstm(
    const bf16* __restrict__ xb16, const bf16* __restrict__ hb16,
    const bf16* __restrict__ wT, const float* __restrict__ b_ih,
    const float* __restrict__ b_hh, const float* __restrict__ cx,
    const float* __restrict__ maskb,
    float* __restrict__ cx_out, bf16* __restrict__ hn16)
{
    int bid = blockIdx.x;
    int n  = bid & 7;
    int i  = bid >> 3;          // 0..31
    int mt = i & 3, nt = i >> 2;
    int b0 = mt*256, d0 = nt*64;

    int t = threadIdx.x;
    int w = t >> 6, l = t & 63;
    int wr = w >> 2, wc = w & 3;          // row-half, gate
    int quad = l >> 4, l16 = l & 15;

    __shared__ __align__(16) bf16 lds[4*16384];   // 4 bufs x (A 256x32 | B 256x32) = 128 KB

    int G0 = t;                                   // granule id, instr0; instr1 = +512
    int rowA0 = G0>>2, rowA1 = rowA0 + 128;
    int ksA0 = (G0&3) ^ ((rowA0>>1)&3);
    int ksA1 = (G0&3) ^ ((rowA1>>1)&3);
    const bf16* xbP0 = xb16 + (size_t)(b0+rowA0)*4096 + n*512 + ksA0*8;
    const bf16* hbP0 = hb16 + (size_t)(b0+rowA0)*4096 + n*512 + ksA0*8;
    const bf16* xbP1 = xb16 + (size_t)(b0+rowA1)*4096 + n*512 + ksA1*8;
    const bf16* hbP1 = hb16 + (size_t)(b0+rowA1)*4096 + n*512 + ksA1*8;

    int vc0 = G0>>2, vc1 = vc0 + 128;             // vcol = g*64 + dl
    int ksB0 = (G0&3) ^ ((vc0>>1)&3);
    int ksB1 = (G0&3) ^ ((vc1>>1)&3);
    const bf16* wb = wT + (size_t)n*2048*1024;
    const bf16* wP0 = wb + (size_t)((vc0>>6)*512 + d0 + (vc0&63))*1024 + ksB0*8;
    const bf16* wP1 = wb + (size_t)((vc1>>6)*512 + d0 + (vc1&63))*1024 + ksB1*8;

    int offA[8], offB[4];
    #pragma unroll
    for (int m=0;m<8;++m){ int R = wr*128 + m*16 + l16; offA[m] = (R*4 + (quad ^ ((R>>1)&3)))*8; }
    #pragma unroll
    for (int nf=0;nf<4;++nf){ int C = wc*64 + nf*16 + l16; offB[nf] = (C*4 + (quad ^ ((C>>1)&3)))*8; }

    auto stA = [&](int buf, int kt){
        const bf16* s0 = (kt<16 ? xbP0 : hbP0) + (kt&15)*32;
        const bf16* s1 = (kt<16 ? xbP1 : hbP1) + (kt&15)*32;
        bf16* dst = &lds[buf*16384 + w*512];
        gload16(s0, dst);
        gload16(s1, dst + 4096);
    };
    auto stB = [&](int buf, int kt){
        bf16* dst = &lds[buf*16384 + 8192 + w*512];
        gload16(wP0 + kt*32, dst);
        gload16(wP1 + kt*32, dst + 4096);
    };

    f32x4 zero = {0.f,0.f,0.f,0.f};
    f32x4 acc[8][4];
    #pragma unroll
    for (int m=0;m<8;++m)
        #pragma unroll
        for (int nf=0;nf<4;++nf) acc[m][nf] = zero;

    stA(0,0); stB(0,0);
    stA(1,1); stB(1,1);
    WAITVM(4);
    sbar();

    #pragma unroll 2
    for (int kt=0; kt<32; ++kt){
        int buf = kt & 3;
        const bf16* Ab = &lds[buf*16384];
        const bf16* Bb = Ab + 8192;

        if (kt < 30){ stA((kt+2)&3, kt+2); stB((kt+2)&3, kt+2); }

        bf16x8 av[8], bv[4];
        #pragma unroll
        for (int m=0;m<8;++m) av[m] = *(const bf16x8*)&Ab[offA[m]];
        #pragma unroll
        for (int nf=0;nf<4;++nf) bv[nf] = *(const bf16x8*)&Bb[offB[nf]];

        __builtin_amdgcn_s_setprio(1);
        #pragma unroll
        for (int m=0;m<8;++m)
            #pragma unroll
            for (int nf=0;nf<4;++nf)
                acc[m][nf] = __builtin_amdgcn_mfma_f32_16x16x32_bf16(av[m], bv[nf], acc[m][nf], 0,0,0);
        __builtin_amdgcn_s_setprio(0);

        // tile kt+1 gate: 8 outstanding, newest 4 = kt+2 -> vmcnt(4); tail drains.
        if (kt < 30) { WAITVM(4); } else { WAITVM(0); }
        sbar();
    }

    float* gbuf = (float*)lds;          // reuse: 64 x 260 f32 = 66.5 KB
    const int GP = 260;
    int dl_t = t & 63;
    int i_t  = t >> 6;                  // 0..7 -> row group
    int d = d0 + dl_t;
    float bi  = b_ih[n*2048 +        d] + b_hh[n*2048 +        d];
    float bff = b_ih[n*2048 +  512 + d] + b_hh[n*2048 +  512 + d];
    float bg  = b_ih[n*2048 + 1024 + d] + b_hh[n*2048 + 1024 + d];
    float bo  = b_ih[n*2048 + 1536 + d] + b_hh[n*2048 + 1536 + d];

    #pragma unroll
    for (int c=0; c<4; ++c){            // 64-row chunks: rows [c*64, c*64+64)
        if (wr == (c>>1)){
            #pragma unroll
            for (int mm=0; mm<4; ++mm)
                #pragma unroll
                for (int nf=0; nf<4; ++nf)
                    #pragma unroll
                    for (int v=0; v<4; ++v)
                        gbuf[(mm*16 + quad*4 + v)*GP + wc*64 + nf*16 + l16] = acc[(c&1)*4 + mm][nf][v];
        }
        __syncthreads();
        #pragma unroll
        for (int r=0; r<8; ++r){
            int row_l = i_t*8 + r;
            int row_g = b0 + c*64 + row_l;
            float gi = gbuf[row_l*GP +       dl_t] + bi;
            float gf = gbuf[row_l*GP +  64 + dl_t] + bff;
            float gg = gbuf[row_l*GP + 128 + dl_t] + bg;
            float go = gbuf[row_l*GP + 192 + dl_t] + bo;
            size_t gidx = (size_t)row_g*4096 + n*512 + d;
            float cb = cx[gidx];
            float cn = sigf(gf)*cb + sigf(gi)*ftanh(gg);
            float hn = sigf(go)*ftanh(cn);
            float mk = maskb[row_g*8 + n];
            cx_out[gidx] = (mk != 0.f) ? cn : cb;
            hn16[gidx]   = (bf16)hn;
        }
        __syncthreads();
    }
}

// ---------------------------------------------------------------- qkv2 = hn @ mha_w{q,k,v} (v2: T3/T4 ring)
// 3-buf LDS ring, stage tile it+2, counted WAITVM(2) (2 loads/thread/stage),
// ONE raw barrier per K-step (16 vs 32), setprio around the MFMA quad.
__global__ __launch_bounds__(256) void k_proj64(const bf16* __restrict__ hn16,
                                                const bf16* __restrict__ wqkvT,
                                                float* __restrict__ qkv2)
{
    int b0 = blockIdx.x*64, n = blockIdx.y, ct = blockIdx.z;
    int t = threadIdx.x, w = t>>6, l = t&63, quad = l>>4, l16 = l&15;
    int wm = w&1, wd = w>>1;
    __shared__ __align__(16) bf16 A_s[3][256*8];
    __shared__ __align__(16) bf16 B_s[3][256*8];
    f32x4 zero = {0.f,0.f,0.f,0.f};
    f32x4 acc[2][2] = {{zero,zero},{zero,zero}};
    const bf16* ab = hn16 + (size_t)n*512;
    const bf16* wb = wqkvT + ((size_t)n*192 + ct*64)*512;

    int row = t>>2, ss = t&3;
    int seg = ss ^ ((row>>1)&3);
    const bf16* aP = ab + (size_t)(b0+row)*4096 + seg*8;
    const bf16* bP = wb + (size_t)row*512      + seg*8;

    auto stage = [&](int buf, int kt){
        gload16(aP + kt*32, &A_s[buf][(w*64)*8]);
        gload16(bP + kt*32, &B_s[buf][(w*64)*8]);
    };

    stage(0, 0);
    stage(1, 1);
    WAITVM(2);
    sbar();

    int buf = 0;
    #pragma unroll 1
    for (int it=0; it<16; ++it){
        int nb = (buf==0) ? 2 : buf-1;      // (buf+2)%3
        if (it < 14) stage(nb, it+2);
        bf16x8 a[2], bb[2];
        #pragma unroll
        for (int r=0;r<2;++r){
            int rr = wm*32 + r*16 + l16;
            int slot = rr*4 + (quad ^ ((rr>>1)&3));
            a[r] = *(const bf16x8*)&A_s[buf][slot*8];
        }
        #pragma unroll
        for (int c=0;c<2;++c){
            int col = wd*32 + c*16 + l16;
            int slot = col*4 + (quad ^ ((col>>1)&3));
            bb[c] = *(const bf16x8*)&B_s[buf][slot*8];
        }
        __builtin_amdgcn_s_setprio(1);
        #pragma unroll
        for (int r=0;r<2;++r)
            #pragma unroll
            for (int c=0;c<2;++c)
                acc[r][c] = __builtin_amdgcn_mfma_f32_16x16x32_bf16(a[r], bb[c], acc[r][c], 0,0,0);
        __builtin_amdgcn_s_setprio(0);
        if (it < 14) { WAITVM(2); } else { WAITVM(0); }
        sbar();
        buf = (buf==2) ? 0 : buf+1;
    }
    #pragma unroll
    for (int c=0;c<2;++c){
        int col = ct*64 + wd*32 + c*16 + l16;
        #pragma unroll
        for (int r=0;r<2;++r)
            #pragma unroll
            for (int v=0;v<4;++v){
                int rr = b0 + wm*32 + r*16 + quad*4 + v;
                qkv2[(size_t)rr*1536 + n*192 + col] = acc[r][c][v];
            }
    }
}

// ---------------------------------------------------------------- mha attention + fc/gate + masked output (fused)
// v4: 512 threads, 4 b per block (128 threads / 2 waves per b) -> 8 waves/CU.
__global__ __launch_bounds__(512) void k_att2fc(const float* __restrict__ qkv2,
                                                const bf16* __restrict__ fcgT,
                                                const float* __restrict__ fc_b,
                                                const float* __restrict__ gate_b,
                                                const bf16* __restrict__ hn16,
                                                const float* __restrict__ hx,
                                                const float* __restrict__ maskb,
                                                float* __restrict__ hx_out)
{
    int t = threadIdx.x;
    int sb = t>>7, ts = t&127;
    int wv = (t>>6)&1, lw = t&63;
    int b = blockIdx.x*4 + sb;
    __shared__ float q_s[4][512];
    __shared__ float k_s[4][512];
    __shared__ float v_s[4][512];
    __shared__ float at_s[4][64];
    __shared__ bf16 o_s[32][72];
    #pragma unroll
    for (int r=0;r<4;++r){
        int i = ts + r*128;
        int n = i>>6, e = i&63;
        const float* src = qkv2 + (size_t)b*1536 + n*192;
        q_s[sb][i] = src[e];
        k_s[sb][i] = src[64+e];
        v_s[sb][i] = src[128+e];
    }
    __syncthreads();
    {
        int n = wv*4 + (lw>>4);          // 4 n per wave
        int j = (lw>>1)&7;               // 8 j
        int eh = lw&1;                   // 2 e-halves of 32
        const float* q = &q_s[sb][n*64 + eh*32];
        const float* k = &k_s[sb][j*64 + eh*32];
        float s = 0.f;
        #pragma unroll
        for (int e=0;e<32;++e) s += q[e]*k[e];
        s += __shfl_xor(s, 1);
        if (eh==0) at_s[sb][n*8+j] = s*0.125f;
    }
    __syncthreads();
    if (lw < 4){
        int n = wv*4 + lw;
        float m = at_s[sb][n*8];
        for (int j=1;j<8;++j) m = fmaxf(m, at_s[sb][n*8+j]);
        float ex[8]; float sum=0.f;
        for (int j=0;j<8;++j){ ex[j]=__expf(at_s[sb][n*8+j]-m); sum+=ex[j]; }
        float inv = 1.f/sum;
        for (int j=0;j<8;++j) at_s[sb][n*8+j] = ex[j]*inv;
    }
    __syncthreads();
    #pragma unroll
    for (int r=0;r<4;++r){
        int i = ts + r*128;
        int n = i>>6, e = i&63;
        float s = 0.f;
        #pragma unroll
        for (int j=0;j<8;++j) s += at_s[sb][n*8+j]*v_s[sb][j*64+e];
        o_s[sb*8+n][e] = (bf16)s;
    }
    __syncthreads();
    // ---- fused fc+gate: M=32, N=1024 over 8 waves (wd = 4 chunks of 256), K=64 ----
    {
        int w = t>>6, l = t&63, quad = l>>4, l16 = l&15;
        int wm = w&1, wd = w>>1;         // wd 0..3
        bf16x8 a0 = *(const bf16x8*)&o_s[wm*16 + l16][quad*8];
        bf16x8 a1 = *(const bf16x8*)&o_s[wm*16 + l16][32 + quad*8];
        f32x4 zero = {0.f,0.f,0.f,0.f};
        f32x4 acc[16];
        #pragma unroll
        for (int nt=0; nt<16; ++nt){
            int cg = wd*256 + nt*16 + l16;
            bf16x8 b0 = *(const bf16x8*)&fcgT[(size_t)cg*64 + quad*8];
            bf16x8 b1 = *(const bf16x8*)&fcgT[(size_t)cg*64 + 32 + quad*8];
            acc[nt] = __builtin_amdgcn_mfma_f32_16x16x32_bf16(a0, b0, zero, 0,0,0);
            acc[nt] = __builtin_amdgcn_mfma_f32_16x16x32_bf16(a1, b1, acc[nt], 0,0,0);
        }
        #pragma unroll
        for (int ctl=0; ctl<4; ++ctl){
            int ct = wd*4 + ctl;
            #pragma unroll
            for (int s=0; s<2; ++s){
                int d = ct*32 + s*16 + l16;
                float fb = fc_b[d], gb = gate_b[d];
                f32x4 fa = acc[ctl*4+s], ga = acc[ctl*4+2+s];
                #pragma unroll
                for (int v=0; v<4; ++v){
                    int rm = wm*16 + quad*4 + v;
                    int bb = blockIdx.x*4 + (rm>>3), nn = rm&7;
                    size_t idx = (size_t)bb*4096 + nn*512 + d;
                    float f = fa[v] + fb;
                    float g = ga[v] + gb;
                    float hnv = (float)hn16[idx];
                    float mk = maskb[bb*8+nn];
                    hx_out[idx] = (mk != 0.f) ? (hnv + sigf(g)*ftanh(f)) : hx[idx];
                }
            }
        }
    }
}

// ----------------------------------------------------------------
extern "C" void kernel_launch(void* const* d_in, const int* in_sizes, int n_in,
                              void* d_out, int out_size, void* d_ws, size_t ws_size,
                              hipStream_t stream)
{
    const float* inp       = (const float*)d_in[0];
    const float* hx        = (const float*)d_in[1];
    const float* cx        = (const float*)d_in[2];
    const float* ia_wq     = (const float*)d_in[3];
    const float* ia_wk     = (const float*)d_in[4];
    const float* ia_wv     = (const float*)d_in[5];
    const float* ia_fc_w   = (const float*)d_in[6];
    const float* ia_fc_b   = (const float*)d_in[7];
    const float* mha_wq    = (const float*)d_in[8];
    const float* mha_wk    = (const float*)d_in[9];
    const float* mha_wv    = (const float*)d_in[10];
    const float* mha_fc_w  = (const float*)d_in[11];
    const float* mha_fc_b  = (const float*)d_in[12];
    const float* mha_gate_w= (const float*)d_in[13];
    const float* mha_gate_b= (const float*)d_in[14];
    const float* w_ih      = (const float*)d_in[15];
    const float* w_hh      = (const float*)d_in[16];
    const float* b_ih      = (const float*)d_in[17];
    const float* b_hh      = (const float*)d_in[18];

    float* hx_out  = (float*)d_out;
    float* cx_out  = hx_out + (size_t)B_*NHID_;
    float* mask_out= cx_out + (size_t)B_*NHID_;

    char* p = (char*)d_ws;
    bf16* wT     = (bf16*)p;               p += (size_t)8*2048*1024*2;   // 32 MB
    bf16* hb16   = (bf16*)p;               p += (size_t)B_*NHID_*2;      // 8 MB
    bf16* xb16   = (bf16*)p;               p += (size_t)B_*NHID_*2;      // 8 MB
    bf16* hn16   = (bf16*)p;               p += (size_t)B_*NHID_*2;      // 8 MB
    bf16* wqkvT  = (bf16*)p;               p += (size_t)8*192*512*2;     // 1.5 MB
    bf16* iafcT  = (bf16*)p;               p += (size_t)512*64*2;        // 64 KB
    bf16* fcgT   = (bf16*)p;               p += (size_t)1024*64*2;       // 128 KB
    float* qbufH = (float*)p;              p += (size_t)2*B_*512*4;      // 4 MB (2 K-halves)
    float* kbufH = (float*)p;              p += (size_t)2*B_*256*4;      // 2 MB
    float* vbufH = (float*)p;              p += (size_t)2*B_*256*4;      // 2 MB
    float* qkv2  = (float*)p;              p += (size_t)B_*1536*4;       // 6 MB
    float* maskb = (float*)p;              p += (size_t)B_*8*4;          // 32 KB

    hipLaunchKernelGGL(k_prepqkv, dim3(9176), dim3(256), 0, stream,
                       w_ih, w_hh, hx, inp, ia_wq, ia_wk, ia_wv,
                       mha_wq, mha_wk, mha_wv, ia_fc_w, mha_fc_w, mha_gate_w,
                       wT, hb16, wqkvT, iafcT, fcgT, qbufH, kbufH, vbufH);
    hipLaunchKernelGGL(k_score, dim3(256), dim3(512), 0, stream,
                       qbufH, kbufH, vbufH, iafcT, ia_fc_b, xb16, maskb, mask_out);
    hipLaunchKernelGGL(k_lstm, dim3(256), dim3(512), 0, stream,
                       xb16, hb16, wT, b_ih, b_hh, cx, maskb, cx_out, hn16);
    hipLaunchKernelGGL(k_proj64, dim3(16,8,3), dim3(256), 0, stream, hn16, wqkvT, qkv2);
    hipLaunchKernelGGL(k_att2fc, dim3(256), dim3(512), 0, stream,
                       qkv2, fcgT, mha_fc_b, mha_gate_b, hn16, hx, maskb, hx_out);
}

// Round 11
// 272.244 us; speedup vs baseline: 1.0093x; 1.0093x over previous
//
#include <hip/hip_runtime.h>
#include <hip/hip_bf16.h>

#define B_    1024
#define NHID_ 4096
#define NBO   8
#define BSO   512
#define DK_   64

typedef __bf16 bf16;
typedef __bf16 bf16x2 __attribute__((ext_vector_type(2)));
typedef __bf16 bf16x4 __attribute__((ext_vector_type(4)));
typedef __bf16 bf16x8 __attribute__((ext_vector_type(8)));
typedef float  f32x4  __attribute__((ext_vector_type(4)));

__device__ __forceinline__ float sigf(float x){
    float e = __expf(-x);
    return __builtin_amdgcn_rcpf(1.0f + e);
}
__device__ __forceinline__ float ftanh(float x){
    float e = __expf(2.0f*x);
    return 1.0f - 2.0f*__builtin_amdgcn_rcpf(e + 1.0f);
}

// async global->LDS, 16B per lane; lds dest is wave-uniform base (+lane*16 implicit)
__device__ __forceinline__ void gload16(const void* g, void* lds){
    __builtin_amdgcn_global_load_lds((const __attribute__((address_space(1))) unsigned int*)g,
                                     (__attribute__((address_space(3))) unsigned int*)lds,
                                     16, 0, 0);
}

// raw barrier without the compiler's vmcnt(0) drain; empty asm pins memory ops
__device__ __forceinline__ void sbar(){
    asm volatile("" ::: "memory");
    __builtin_amdgcn_s_barrier();
    asm volatile("" ::: "memory");
}
#define WAITVM(N) asm volatile("s_waitcnt vmcnt(" #N ")" ::: "memory")

// ---------------------------------------------------------------- merged prep + qkv (v2):
// bid < 768:      input-attn q/k/v GEMMs (fp32 exact, K-split z)
// next 4096:      w_ih/w_hh -> bf16 transposed wT[n][gcol2048][k1024]
// next 4096:      hx -> bf16
// next 192:       mha qkv weight tile-transpose
// next 8:         ia_fc tile-transpose
// next 16:        fc|gate paired tile-transpose
__global__ __launch_bounds__(256) void k_prepqkv(
    const float* __restrict__ w_ih, const float* __restrict__ w_hh,
    const float* __restrict__ hx, const float* __restrict__ inp,
    const float* __restrict__ ia_wq, const float* __restrict__ ia_wk,
    const float* __restrict__ ia_wv,
    const float* __restrict__ mha_wq, const float* __restrict__ mha_wk,
    const float* __restrict__ mha_wv, const float* __restrict__ ia_fc_w,
    const float* __restrict__ fc_w, const float* __restrict__ gate_w,
    bf16* __restrict__ wT, bf16* __restrict__ hb16, bf16* __restrict__ wqkvT,
    bf16* __restrict__ iafcT, bf16* __restrict__ fcgT,
    float* __restrict__ qbufH, float* __restrict__ kbufH, float* __restrict__ vbufH)
{
    int bid = blockIdx.x;
    int t = threadIdx.x;
    __shared__ float Af[32][36];
    __shared__ float W1[32][68];
    __shared__ float W2[32][68];
    __shared__ float tile[64][65];

    if (bid < 768){
        int z = (bid >= 384) ? 1 : 0;
        int r = bid - z*384;
        int y = r >> 5, b0 = (r & 31)*32;
        int tx = t&15, ty = t>>4;
        if (y < 8){
            int n = y;
            float acc[2][4] = {};
            for (int k0=z*256; k0<z*256+256; k0+=32){
                { int row=t>>3, c4=(t&7)*4;
                  *(float4*)&Af[row][c4] = *(const float4*)&hx[(size_t)(b0+row)*4096 + n*512 + k0 + c4]; }
                #pragma unroll
                for (int j=0;j<2;++j){
                    int id = j*256 + t;
                    int kk = id>>4, e4 = (id&15)*4;
                    *(float4*)&W1[kk][e4] = *(const float4*)&ia_wq[(size_t)n*32768 + (size_t)(k0+kk)*64 + e4];
                }
                __syncthreads();
                #pragma unroll
                for (int kk4=0; kk4<8; ++kk4){
                    float4 a0 = *(float4*)&Af[ty*2  ][kk4*4];
                    float4 a1 = *(float4*)&Af[ty*2+1][kk4*4];
                    #pragma unroll
                    for (int j=0;j<4;++j){
                        float4 wv = *(float4*)&W1[kk4*4+j][tx*4];
                        float s0 = (j==0)?a0.x:((j==1)?a0.y:((j==2)?a0.z:a0.w));
                        float s1 = (j==0)?a1.x:((j==1)?a1.y:((j==2)?a1.z:a1.w));
                        acc[0][0]+=s0*wv.x; acc[0][1]+=s0*wv.y; acc[0][2]+=s0*wv.z; acc[0][3]+=s0*wv.w;
                        acc[1][0]+=s1*wv.x; acc[1][1]+=s1*wv.y; acc[1][2]+=s1*wv.z; acc[1][3]+=s1*wv.w;
                    }
                }
                __syncthreads();
            }
            #pragma unroll
            for (int r2=0;r2<2;++r2){
                float4 o; o.x=acc[r2][0]; o.y=acc[r2][1]; o.z=acc[r2][2]; o.w=acc[r2][3];
                *(float4*)&qbufH[((size_t)(z*B_ + b0+ty*2+r2))*512 + n*64 + tx*4] = o;
            }
        } else {
            int jb = y-8;
            float ak[2][4] = {}, av[2][4] = {};
            for (int k0=z*64; k0<z*64+64; k0+=32){
                { int row=t>>3, c4=(t&7)*4;
                  *(float4*)&Af[row][c4] = *(const float4*)&inp[(size_t)(b0+row)*512 + jb*128 + k0 + c4]; }
                #pragma unroll
                for (int j=0;j<2;++j){
                    int id = j*256 + t;
                    int kk = id>>4, e4 = (id&15)*4;
                    *(float4*)&W1[kk][e4] = *(const float4*)&ia_wk[(size_t)jb*8192 + (size_t)(k0+kk)*64 + e4];
                    *(float4*)&W2[kk][e4] = *(const float4*)&ia_wv[(size_t)jb*8192 + (size_t)(k0+kk)*64 + e4];
                }
                __syncthreads();
                #pragma unroll
                for (int kk4=0; kk4<8; ++kk4){
                    float4 a0 = *(float4*)&Af[ty*2  ][kk4*4];
                    float4 a1 = *(float4*)&Af[ty*2+1][kk4*4];
                    #pragma unroll
                    for (int j=0;j<4;++j){
                        float4 wk = *(float4*)&W1[kk4*4+j][tx*4];
                        float4 wv = *(float4*)&W2[kk4*4+j][tx*4];
                        float s0 = (j==0)?a0.x:((j==1)?a0.y:((j==2)?a0.z:a0.w));
                        float s1 = (j==0)?a1.x:((j==1)?a1.y:((j==2)?a1.z:a1.w));
                        ak[0][0]+=s0*wk.x; ak[0][1]+=s0*wk.y; ak[0][2]+=s0*wk.z; ak[0][3]+=s0*wk.w;
                        ak[1][0]+=s1*wk.x; ak[1][1]+=s1*wk.y; ak[1][2]+=s1*wk.z; ak[1][3]+=s1*wk.w;
                        av[0][0]+=s0*wv.x; av[0][1]+=s0*wv.y; av[0][2]+=s0*wv.z; av[0][3]+=s0*wv.w;
                        av[1][0]+=s1*wv.x; av[1][1]+=s1*wv.y; av[1][2]+=s1*wv.z; av[1][3]+=s1*wv.w;
                    }
                }
                __syncthreads();
            }
            #pragma unroll
            for (int r2=0;r2<2;++r2){
                float4 ok; ok.x=ak[r2][0]; ok.y=ak[r2][1]; ok.z=ak[r2][2]; ok.w=ak[r2][3];
                float4 ov; ov.x=av[r2][0]; ov.y=av[r2][1]; ov.z=av[r2][2]; ov.w=av[r2][3];
                *(float4*)&kbufH[((size_t)(z*B_ + b0+ty*2+r2))*256 + jb*64 + tx*4] = ok;
                *(float4*)&vbufH[((size_t)(z*B_ + b0+ty*2+r2))*256 + jb*64 + tx*4] = ov;
            }
        }
        return;
    }
    bid -= 768;
    if (bid < 4096){
        int c0 = (bid & 31)*64;
        int k0 = ((bid>>5)&7)*64;
        int z  = bid>>8;
        int n = z>>1, which = z&1;
        const float* src = (which ? w_hh : w_ih) + (size_t)n*512*2048;
        #pragma unroll
        for (int it=0; it<4; ++it){
            int idx = t + it*256;
            int r = idx>>4, c4 = (idx&15)*4;
            *(float4*)&tile[r][c4] = *(const float4*)&src[(size_t)(k0+r)*2048 + c0 + c4];
        }
        __syncthreads();
        #pragma unroll
        for (int it=0; it<2; ++it){
            int idx = t + it*256;
            int c = idx>>3, r8 = (idx&7)*8;
            bf16x8 v;
            #pragma unroll
            for (int jj=0;jj<8;++jj) v[jj] = (bf16)tile[r8+jj][c];
            *(bf16x8*)&wT[((size_t)n*2048 + c0 + c)*1024 + which*512 + k0 + r8] = v;
        }
        return;
    }
    bid -= 4096;
    if (bid < 4096){
        int gid = bid*256 + t;
        float4 v = ((const float4*)hx)[gid];
        bf16x4 o; o.x=(bf16)v.x; o.y=(bf16)v.y; o.z=(bf16)v.z; o.w=(bf16)v.w;
        *(bf16x4*)&hb16[(size_t)gid*4] = o;
        return;
    }
    bid -= 4096;
    if (bid < 192){   // wqkvT[(n*192 + p*64 + ee)*512 + k] = mha_wX[n][k][ee], 64k x 64ee tiles
        int kt = bid & 7, np = bid >> 3;
        int n = np / 3, p = np - n*3;
        int k0 = kt*64;
        const float* s = (p==0) ? mha_wq : ((p==1) ? mha_wk : mha_wv);
        #pragma unroll
        for (int it=0; it<4; ++it){
            int r = it*16 + (t>>4), c4 = (t&15)*4;
            *(float4*)&tile[r][c4] = *(const float4*)&s[((size_t)n*512 + k0 + r)*64 + c4];
        }
        __syncthreads();
        #pragma unroll
        for (int it=0; it<2; ++it){
            int idx = it*256 + t;
            int ee = idx>>3, k8 = (idx&7)*8;
            bf16x8 v;
            #pragma unroll
            for (int jj=0;jj<8;++jj) v[jj] = (bf16)tile[k8+jj][ee];
            *(bf16x8*)&wqkvT[((size_t)n*192 + p*64 + ee)*512 + k0 + k8] = v;
        }
        return;
    }
    bid -= 192;
    if (bid < 8){     // iafcT[c*64 + k] = ia_fc_w[k*512 + c], 64k x 64c tiles
        int c0 = bid*64;
        #pragma unroll
        for (int it=0; it<4; ++it){
            int k = it*16 + (t>>4), c4 = (t&15)*4;
            *(float4*)&tile[k][c4] = *(const float4*)&ia_fc_w[(size_t)k*512 + c0 + c4];
        }
        __syncthreads();
        #pragma unroll
        for (int it=0; it<2; ++it){
            int idx = it*256 + t;
            int cc = idx>>3, k8 = (idx&7)*8;
            bf16x8 v;
            #pragma unroll
            for (int jj=0;jj<8;++jj) v[jj] = (bf16)tile[k8+jj][cc];
            *(bf16x8*)&iafcT[(size_t)(c0+cc)*64 + k8] = v;
        }
        return;
    }
    bid -= 8;
    if (bid < 16){    // fcgT[(ct*64+j)*64 + k]: j<32 fc cols ct*32+j, j>=32 gate cols ct*32+j-32
        int ct = bid;
        #pragma unroll
        for (int it=0; it<4; ++it){
            int k = it*16 + (t>>4);
            int seg = t&15;
            int j4 = seg*4;
            const float* s = (seg < 8) ? &fc_w[(size_t)k*512 + ct*32 + j4]
                                       : &gate_w[(size_t)k*512 + ct*32 + (j4-32)];
            *(float4*)&tile[k][j4] = *(const float4*)s;
        }
        __syncthreads();
        #pragma unroll
        for (int it=0; it<2; ++it){
            int idx = it*256 + t;
            int j = idx>>3, k8 = (idx&7)*8;
            bf16x8 v;
            #pragma unroll
            for (int jj=0;jj<8;++jj) v[jj] = (bf16)tile[k8+jj][j];
            *(bf16x8*)&fcgT[(size_t)(ct*64 + j)*64 + k8] = v;
        }
    }
}

// ---------------------------------------------------------------- scores + softmax + top4 + o + fc_ia MFMA (fused)
// v4: 512 threads, 4 b per block (128 threads / 2 waves per b) -> 8 waves/CU (2/SIMD).
__global__ __launch_bounds__(512) void k_score(const float* __restrict__ qbufH,
                                               const float* __restrict__ kbufH,
                                               const float* __restrict__ vbufH,
                                               const bf16* __restrict__ iafcT,
                                               const float* __restrict__ ia_fc_b,
                                               bf16* __restrict__ xb16,
                                               float* __restrict__ maskb,
                                               float* __restrict__ mask_out)
{
    int t = threadIdx.x;
    int sb = t>>7, ts = t&127;           // b-group, thread-in-group
    int wv = (t>>6)&1, lw = t&63;        // wave-half of group, lane
    int b = blockIdx.x*4 + sb;
    __shared__ float q_s[4][512];
    __shared__ float k_s[4][256];
    __shared__ float v_s[4][256];
    __shared__ float at_s[4][40];
    __shared__ float sc_s[4][8];
    __shared__ float mb_s[4][8];
    __shared__ bf16 o_s[32][72];

    #pragma unroll
    for (int r=0;r<4;++r){
        int i = ts + r*128;
        q_s[sb][i] = qbufH[(size_t)b*512 + i] + qbufH[(size_t)(B_+b)*512 + i];
    }
    #pragma unroll
    for (int r=0;r<2;++r){
        int i = ts + r*128;
        k_s[sb][i] = kbufH[(size_t)b*256 + i] + kbufH[(size_t)(B_+b)*256 + i];
        v_s[sb][i] = vbufH[(size_t)b*256 + i] + vbufH[(size_t)(B_+b)*256 + i];
    }
    __syncthreads();
    {
        int n = wv*4 + (lw>>4);          // 4 n per wave
        int j = (lw>>2)&3;               // 4 j
        int ec = lw&3;                   // 4 e-chunks of 16
        const float* q = &q_s[sb][n*64 + ec*16];
        const float* k = &k_s[sb][j*64 + ec*16];
        float s = 0.f;
        #pragma unroll
        for (int e=0;e<16;++e) s += q[e]*k[e];
        s += __shfl_xor(s, 1);
        s += __shfl_xor(s, 2);
        if (ec==0) at_s[sb][n*5+j] = s*0.125f;
        if ((lw&15)==4) at_s[sb][n*5+4] = 0.f;
    }
    __syncthreads();
    if (lw < 4){                         // each wave: softmax for its 4 n's
        int n = wv*4 + lw;
        float m = at_s[sb][n*5];
        for (int j=1;j<5;++j) m = fmaxf(m, at_s[sb][n*5+j]);
        float ex[5]; float sum=0.f;
        for (int j=0;j<5;++j){ ex[j]=__expf(at_s[sb][n*5+j]-m); sum+=ex[j]; }
        float inv = 1.f/sum;
        for (int j=0;j<5;++j) at_s[sb][n*5+j] = ex[j]*inv;
        sc_s[sb][n] = ex[0]*inv;
    }
    __syncthreads();
    if (ts == 0){
        float s[8];
        for (int nn=0;nn<8;++nn) s[nn] = sc_s[sb][nn];
        for (int ii=1;ii<8;++ii){ float key=s[ii]; int jj=ii-1;
            while(jj>=0 && s[jj]<key){ s[jj+1]=s[jj]; --jj; } s[jj+1]=key; }
        float thr = s[3]-0.01f;
        for (int nn=0;nn<8;++nn) mb_s[sb][nn] = (sc_s[sb][nn] > thr) ? 1.0f : 0.0f;
    }
    __syncthreads();
    #pragma unroll
    for (int r=0;r<4;++r){
        int i = ts + r*128;
        int n = i>>6, e = i&63;
        float s = 0.f;
        #pragma unroll
        for (int j=0;j<4;++j) s += at_s[sb][n*5+j]*v_s[sb][j*64+e];
        o_s[sb*8+n][e] = (bf16)s;
    }
    if (ts < 8) maskb[b*8+ts] = mb_s[sb][ts];
    float4* mo = (float4*)(mask_out + (size_t)b*4096);
    #pragma unroll
    for (int r=0;r<8;++r){
        int i4 = ts + r*128;
        float m = mb_s[sb][i4>>7];
        float4 mv; mv.x=m; mv.y=m; mv.z=m; mv.w=m;
        mo[i4] = mv;
    }
    __syncthreads();
    // ---- fused fc_ia: M=32 (4b x 8n), N=512 over 8 waves (wd = 4 N-chunks), K=64 ----
    {
        int w = t>>6, l = t&63, quad = l>>4, l16 = l&15;
        int wm = w&1, wd = w>>1;         // wd 0..3
        bf16x8 a0 = *(const bf16x8*)&o_s[wm*16 + l16][quad*8];
        bf16x8 a1 = *(const bf16x8*)&o_s[wm*16 + l16][32 + quad*8];
        f32x4 zero = {0.f,0.f,0.f,0.f};
        #pragma unroll
        for (int nt=0; nt<8; ++nt){
            int cg = wd*128 + nt*16 + l16;
            bf16x8 b0 = *(const bf16x8*)&iafcT[(size_t)cg*64 + quad*8];
            bf16x8 b1 = *(const bf16x8*)&iafcT[(size_t)cg*64 + 32 + quad*8];
            f32x4 acc = __builtin_amdgcn_mfma_f32_16x16x32_bf16(a0, b0, zero, 0,0,0);
            acc = __builtin_amdgcn_mfma_f32_16x16x32_bf16(a1, b1, acc, 0,0,0);
            float bias = ia_fc_b[cg];
            #pragma unroll
            for (int v=0; v<4; ++v){
                int rm = wm*16 + quad*4 + v;
                int bb = blockIdx.x*4 + (rm>>3), nn = rm&7;
                xb16[(size_t)bb*4096 + nn*512 + cg] = (bf16)(acc[v] + bias);
            }
        }
    }
}

// ---------------------------------------------------------------- LSTM gates MFMA + pointwise (v7: proven best)
// 256x256 tile, 512 threads = 8 waves; BK=32, 4-deep LDS ring (128 KB).
// ONE barrier per K-tile: {stage kt+2, 12 ds_reads, 32-MFMA under setprio,
// counted vmcnt(4), s_barrier}. The wait->barrier->read order is REQUIRED:
// LDS buffers are staged cooperatively by all 8 waves and vmcnt is per-wave,
// so cross-wave visibility demands the barrier AFTER all waves' waits (the v8
// frag-prefetch that read before that barrier raced and failed correctness).
__global__ __launch_bounds__(512,2) void k_lstm(
    const bf16* __restrict__ xb16, const bf16* __restrict__ hb16,
    const bf16* __restrict__ wT, const float* __restrict__ b_ih,
    const float* __restrict__ b_hh, const float* __restrict__ cx,
    const float* __restrict__ maskb,
    float* __restrict__ cx_out, bf16* __restrict__ hn16)
{
    int bid = blockIdx.x;
    int n  = bid & 7;
    int i  = bid >> 3;          // 0..31
    int mt = i & 3, nt = i >> 2;
    int b0 = mt*256, d0 = nt*64;

    int t = threadIdx.x;
    int w = t >> 6, l = t & 63;
    int wr = w >> 2, wc = w & 3;          // row-half, gate
    int quad = l >> 4, l16 = l & 15;

    __shared__ __align__(16) bf16 lds[4*16384];   // 4 bufs x (A 256x32 | B 256x32) = 128 KB

    int G0 = t;                                   // granule id, instr0; instr1 = +512
    int rowA0 = G0>>2, rowA1 = rowA0 + 128;
    int ksA0 = (G0&3) ^ ((rowA0>>1)&3);
    int ksA1 = (G0&3) ^ ((rowA1>>1)&3);
    const bf16* xbP0 = xb16 + (size_t)(b0+rowA0)*4096 + n*512 + ksA0*8;
    const bf16* hbP0 = hb16 + (size_t)(b0+rowA0)*4096 + n*512 + ksA0*8;
    const bf16* xbP1 = xb16 + (size_t)(b0+rowA1)*4096 + n*512 + ksA1*8;
    const bf16* hbP1 = hb16 + (size_t)(b0+rowA1)*4096 + n*512 + ksA1*8;

    int vc0 = G0>>2, vc1 = vc0 + 128;             // vcol = g*64 + dl
    int ksB0 = (G0&3) ^ ((vc0>>1)&3);
    int ksB1 = (G0&3) ^ ((vc1>>1)&3);
    const bf16* wb = wT + (size_t)n*2048*1024;
    const bf16* wP0 = wb + (size_t)((vc0>>6)*512 + d0 + (vc0&63))*1024 + ksB0*8;
    const bf16* wP1 = wb + (size_t)((vc1>>6)*512 + d0 + (vc1&63))*1024 + ksB1*8;

    int offA[8], offB[4];
    #pragma unroll
    for (int m=0;m<8;++m){ int R = wr*128 + m*16 + l16; offA[m] = (R*4 + (quad ^ ((R>>1)&3)))*8; }
    #pragma unroll
    for (int nf=0;nf<4;++nf){ int C = wc*64 + nf*16 + l16; offB[nf] = (C*4 + (quad ^ ((C>>1)&3)))*8; }

    auto stA = [&](int buf, int kt){
        const bf16* s0 = (kt<16 ? xbP0 : hbP0) + (kt&15)*32;
        const bf16* s1 = (kt<16 ? xbP1 : hbP1) + (kt&15)*32;
        bf16* dst = &lds[buf*16384 + w*512];
        gload16(s0, dst);
        gload16(s1, dst + 4096);
    };
    auto stB = [&](int buf, int kt){
        bf16* dst = &lds[buf*16384 + 8192 + w*512];
        gload16(wP0 + kt*32, dst);
        gload16(wP1 + kt*32, dst + 4096);
    };

    f32x4 zero = {0.f,0.f,0.f,0.f};
    f32x4 acc[8][4];
    #pragma unroll
    for (int m=0;m<8;++m)
        #pragma unroll
        for (int nf=0;nf<4;++nf) acc[m][nf] = zero;

    stA(0,0); stB(0,0);
    stA(1,1); stB(1,1);
    WAITVM(4);
    sbar();

    #pragma unroll 2
    for (int kt=0; kt<32; ++kt){
        int buf = kt & 3;
        const bf16* Ab = &lds[buf*16384];
        const bf16* Bb = Ab + 8192;

        if (kt < 30){ stA((kt+2)&3, kt+2); stB((kt+2)&3, kt+2); }

        bf16x8 av[8], bv[4];
        #pragma unroll
        for (int m=0;m<8;++m) av[m] = *(const bf16x8*)&Ab[offA[m]];
        #pragma unroll
        for (int nf=0;nf<4;++nf) bv[nf] = *(const bf16x8*)&Bb[offB[nf]];

        __builtin_amdgcn_s_setprio(1);
        #pragma unroll
        for (int m=0;m<8;++m)
            #pragma unroll
            for (int nf=0;nf<4;++nf)
                acc[m][nf] = __builtin_amdgcn_mfma_f32_16x16x32_bf16(av[m], bv[nf], acc[m][nf], 0,0,0);
        __builtin_amdgcn_s_setprio(0);

        // tile kt+1 gate: 8 outstanding, newest 4 = kt+2 -> vmcnt(4); tail drains.
        if (kt < 30) { WAITVM(4); } else { WAITVM(0); }
        sbar();
    }

    float* gbuf = (float*)lds;          // reuse: 64 x 260 f32 = 66.5 KB
    const int GP = 260;
    int dl_t = t & 63;
    int i_t  = t >> 6;                  // 0..7 -> row group
    int d = d0 + dl_t;
    float bi  = b_ih[n*2048 +        d] + b_hh[n*2048 +        d];
    float bff = b_ih[n*2048 +  512 + d] + b_hh[n*2048 +  512 + d];
    float bg  = b_ih[n*2048 + 1024 + d] + b_hh[n*2048 + 1024 + d];
    float bo  = b_ih[n*2048 + 1536 + d] + b_hh[n*2048 + 1536 + d];

    #pragma unroll
    for (int c=0; c<4; ++c){            // 64-row chunks: rows [c*64, c*64+64)
        if (wr == (c>>1)){
            #pragma unroll
            for (int mm=0; mm<4; ++mm)
                #pragma unroll
                for (int nf=0; nf<4; ++nf)
                    #pragma unroll
                    for (int v=0; v<4; ++v)
                        gbuf[(mm*16 + quad*4 + v)*GP + wc*64 + nf*16 + l16] = acc[(c&1)*4 + mm][nf][v];
        }
        __syncthreads();
        #pragma unroll
        for (int r=0; r<8; ++r){
            int row_l = i_t*8 + r;
            int row_g = b0 + c*64 + row_l;
            float gi = gbuf[row_l*GP +       dl_t] + bi;
            float gf = gbuf[row_l*GP +  64 + dl_t] + bff;
            float gg = gbuf[row_l*GP + 128 + dl_t] + bg;
            float go = gbuf[row_l*GP + 192 + dl_t] + bo;
            size_t gidx = (size_t)row_g*4096 + n*512 + d;
            float cb = cx[gidx];
            float cn = sigf(gf)*cb + sigf(gi)*ftanh(gg);
            float hn = sigf(go)*ftanh(cn);
            float mk = maskb[row_g*8 + n];
            cx_out[gidx] = (mk != 0.f) ? cn : cb;
            hn16[gidx]   = (bf16)hn;
        }
        __syncthreads();
    }
}

// ---------------------------------------------------------------- qkv2 = hn @ mha_w{q,k,v} (v2: T3/T4 ring)
__global__ __launch_bounds__(256) void k_proj64(const bf16* __restrict__ hn16,
                                                const bf16* __restrict__ wqkvT,
                                                float* __restrict__ qkv2)
{
    int b0 = blockIdx.x*64, n = blockIdx.y, ct = blockIdx.z;
    int t = threadIdx.x, w = t>>6, l = t&63, quad = l>>4, l16 = l&15;
    int wm = w&1, wd = w>>1;
    __shared__ __align__(16) bf16 A_s[3][256*8];
    __shared__ __align__(16) bf16 B_s[3][256*8];
    f32x4 zero = {0.f,0.f,0.f,0.f};
    f32x4 acc[2][2] = {{zero,zero},{zero,zero}};
    const bf16* ab = hn16 + (size_t)n*512;
    const bf16* wb = wqkvT + ((size_t)n*192 + ct*64)*512;

    int row = t>>2, ss = t&3;
    int seg = ss ^ ((row>>1)&3);
    const bf16* aP = ab + (size_t)(b0+row)*4096 + seg*8;
    const bf16* bP = wb + (size_t)row*512      + seg*8;

    auto stage = [&](int buf, int kt){
        gload16(aP + kt*32, &A_s[buf][(w*64)*8]);
        gload16(bP + kt*32, &B_s[buf][(w*64)*8]);
    };

    stage(0, 0);
    stage(1, 1);
    WAITVM(2);
    sbar();

    int buf = 0;
    #pragma unroll 1
    for (int it=0; it<16; ++it){
        int nb = (buf==0) ? 2 : buf-1;      // (buf+2)%3
        if (it < 14) stage(nb, it+2);
        bf16x8 a[2], bb[2];
        #pragma unroll
        for (int r=0;r<2;++r){
            int rr = wm*32 + r*16 + l16;
            int slot = rr*4 + (quad ^ ((rr>>1)&3));
            a[r] = *(const bf16x8*)&A_s[buf][slot*8];
        }
        #pragma unroll
        for (int c=0;c<2;++c){
            int col = wd*32 + c*16 + l16;
            int slot = col*4 + (quad ^ ((col>>1)&3));
            bb[c] = *(const bf16x8*)&B_s[buf][slot*8];
        }
        __builtin_amdgcn_s_setprio(1);
        #pragma unroll
        for (int r=0;r<2;++r)
            #pragma unroll
            for (int c=0;c<2;++c)
                acc[r][c] = __builtin_amdgcn_mfma_f32_16x16x32_bf16(a[r], bb[c], acc[r][c], 0,0,0);
        __builtin_amdgcn_s_setprio(0);
        if (it < 14) { WAITVM(2); } else { WAITVM(0); }
        sbar();
        buf = (buf==2) ? 0 : buf+1;
    }
    #pragma unroll
    for (int c=0;c<2;++c){
        int col = ct*64 + wd*32 + c*16 + l16;
        #pragma unroll
        for (int r=0;r<2;++r)
            #pragma unroll
            for (int v=0;v<4;++v){
                int rr = b0 + wm*32 + r*16 + quad*4 + v;
                qkv2[(size_t)rr*1536 + n*192 + col] = acc[r][c][v];
            }
    }
}

// ---------------------------------------------------------------- mha attention + fc/gate + masked output (fused)
// v4: 512 threads, 4 b per block (128 threads / 2 waves per b) -> 8 waves/CU.
__global__ __launch_bounds__(512) void k_att2fc(const float* __restrict__ qkv2,
                                                const bf16* __restrict__ fcgT,
                                                const float* __restrict__ fc_b,
                                                const float* __restrict__ gate_b,
                                                const bf16* __restrict__ hn16,
                                                const float* __restrict__ hx,
                                                const float* __restrict__ maskb,
                                                float* __restrict__ hx_out)
{
    int t = threadIdx.x;
    int sb = t>>7, ts = t&127;
    int wv = (t>>6)&1, lw = t&63;
    int b = blockIdx.x*4 + sb;
    __shared__ float q_s[4][512];
    __shared__ float k_s[4][512];
    __shared__ float v_s[4][512];
    __shared__ float at_s[4][64];
    __shared__ bf16 o_s[32][72];
    #pragma unroll
    for (int r=0;r<4;++r){
        int i = ts + r*128;
        int n = i>>6, e = i&63;
        const float* src = qkv2 + (size_t)b*1536 + n*192;
        q_s[sb][i] = src[e];
        k_s[sb][i] = src[64+e];
        v_s[sb][i] = src[128+e];
    }
    __syncthreads();
    {
        int n = wv*4 + (lw>>4);          // 4 n per wave
        int j = (lw>>1)&7;               // 8 j
        int eh = lw&1;                   // 2 e-halves of 32
        const float* q = &q_s[sb][n*64 + eh*32];
        const float* k = &k_s[sb][j*64 + eh*32];
        float s = 0.f;
        #pragma unroll
        for (int e=0;e<32;++e) s += q[e]*k[e];
        s += __shfl_xor(s, 1);
        if (eh==0) at_s[sb][n*8+j] = s*0.125f;
    }
    __syncthreads();
    if (lw < 4){
        int n = wv*4 + lw;
        float m = at_s[sb][n*8];
        for (int j=1;j<8;++j) m = fmaxf(m, at_s[sb][n*8+j]);
        float ex[8]; float sum=0.f;
        for (int j=0;j<8;++j){ ex[j]=__expf(at_s[sb][n*8+j]-m); sum+=ex[j]; }
        float inv = 1.f/sum;
        for (int j=0;j<8;++j) at_s[sb][n*8+j] = ex[j]*inv;
    }
    __syncthreads();
    #pragma unroll
    for (int r=0;r<4;++r){
        int i = ts + r*128;
        int n = i>>6, e = i&63;
        float s = 0.f;
        #pragma unroll
        for (int j=0;j<8;++j) s += at_s[sb][n*8+j]*v_s[sb][j*64+e];
        o_s[sb*8+n][e] = (bf16)s;
    }
    __syncthreads();
    // ---- fused fc+gate: M=32, N=1024 over 8 waves (wd = 4 chunks of 256), K=64 ----
    {
        int w = t>>6, l = t&63, quad = l>>4, l16 = l&15;
        int wm = w&1, wd = w>>1;         // wd 0..3
        bf16x8 a0 = *(const bf16x8*)&o_s[wm*16 + l16][quad*8];
        bf16x8 a1 = *(const bf16x8*)&o_s[wm*16 + l16][32 + quad*8];
        f32x4 zero = {0.f,0.f,0.f,0.f};
        f32x4 acc[16];
        #pragma unroll
        for (int nt=0; nt<16; ++nt){
            int cg = wd*256 + nt*16 + l16;
            bf16x8 b0 = *(const bf16x8*)&fcgT[(size_t)cg*64 + quad*8];
            bf16x8 b1 = *(const bf16x8*)&fcgT[(size_t)cg*64 + 32 + quad*8];
            acc[nt] = __builtin_amdgcn_mfma_f32_16x16x32_bf16(a0, b0, zero, 0,0,0);
            acc[nt] = __builtin_amdgcn_mfma_f32_16x16x32_bf16(a1, b1, acc[nt], 0,0,0);
        }
        #pragma unroll
        for (int ctl=0; ctl<4; ++ctl){
            int ct = wd*4 + ctl;
            #pragma unroll
            for (int s=0; s<2; ++s){
                int d = ct*32 + s*16 + l16;
                float fb = fc_b[d], gb = gate_b[d];
                f32x4 fa = acc[ctl*4+s], ga = acc[ctl*4+2+s];
                #pragma unroll
                for (int v=0; v<4; ++v){
                    int rm = wm*16 + quad*4 + v;
                    int bb = blockIdx.x*4 + (rm>>3), nn = rm&7;
                    size_t idx = (size_t)bb*4096 + nn*512 + d;
                    float f = fa[v] + fb;
                    float g = ga[v] + gb;
                    float hnv = (float)hn16[idx];
                    float mk = maskb[bb*8+nn];
                    hx_out[idx] = (mk != 0.f) ? (hnv + sigf(g)*ftanh(f)) : hx[idx];
                }
            }
        }
    }
}

// ----------------------------------------------------------------
extern "C" void kernel_launch(void* const* d_in, const int* in_sizes, int n_in,
                              void* d_out, int out_size, void* d_ws, size_t ws_size,
                              hipStream_t stream)
{
    const float* inp       = (const float*)d_in[0];
    const float* hx        = (const float*)d_in[1];
    const float* cx        = (const float*)d_in[2];
    const float* ia_wq     = (const float*)d_in[3];
    const float* ia_wk     = (const float*)d_in[4];
    const float* ia_wv     = (const float*)d_in[5];
    const float* ia_fc_w   = (const float*)d_in[6];
    const float* ia_fc_b   = (const float*)d_in[7];
    const float* mha_wq    = (const float*)d_in[8];
    const float* mha_wk    = (const float*)d_in[9];
    const float* mha_wv    = (const float*)d_in[10];
    const float* mha_fc_w  = (const float*)d_in[11];
    const float* mha_fc_b  = (const float*)d_in[12];
    const float* mha_gate_w= (const float*)d_in[13];
    const float* mha_gate_b= (const float*)d_in[14];
    const float* w_ih      = (const float*)d_in[15];
    const float* w_hh      = (const float*)d_in[16];
    const float* b_ih      = (const float*)d_in[17];
    const float* b_hh      = (const float*)d_in[18];

    float* hx_out  = (float*)d_out;
    float* cx_out  = hx_out + (size_t)B_*NHID_;
    float* mask_out= cx_out + (size_t)B_*NHID_;

    char* p = (char*)d_ws;
    bf16* wT     = (bf16*)p;               p += (size_t)8*2048*1024*2;   // 32 MB
    bf16* hb16   = (bf16*)p;               p += (size_t)B_*NHID_*2;      // 8 MB
    bf16* xb16   = (bf16*)p;               p += (size_t)B_*NHID_*2;      // 8 MB
    bf16* hn16   = (bf16*)p;               p += (size_t)B_*NHID_*2;      // 8 MB
    bf16* wqkvT  = (bf16*)p;               p += (size_t)8*192*512*2;     // 1.5 MB
    bf16* iafcT  = (bf16*)p;               p += (size_t)512*64*2;        // 64 KB
    bf16* fcgT   = (bf16*)p;               p += (size_t)1024*64*2;       // 128 KB
    float* qbufH = (float*)p;              p += (size_t)2*B_*512*4;      // 4 MB (2 K-halves)
    float* kbufH = (float*)p;              p += (size_t)2*B_*256*4;      // 2 MB
    float* vbufH = (float*)p;              p += (size_t)2*B_*256*4;      // 2 MB
    float* qkv2  = (float*)p;              p += (size_t)B_*1536*4;       // 6 MB
    float* maskb = (float*)p;              p += (size_t)B_*8*4;          // 32 KB

    hipLaunchKernelGGL(k_prepqkv, dim3(9176), dim3(256), 0, stream,
                       w_ih, w_hh, hx, inp, ia_wq, ia_wk, ia_wv,
                       mha_wq, mha_wk, mha_wv, ia_fc_w, mha_fc_w, mha_gate_w,
                       wT, hb16, wqkvT, iafcT, fcgT, qbufH, kbufH, vbufH);
    hipLaunchKernelGGL(k_score, dim3(256), dim3(512), 0, stream,
                       qbufH, kbufH, vbufH, iafcT, ia_fc_b, xb16, maskb, mask_out);
    hipLaunchKernelGGL(k_lstm, dim3(256), dim3(512), 0, stream,
                       xb16, hb16, wT, b_ih, b_hh, cx, maskb, cx_out, hn16);
    hipLaunchKernelGGL(k_proj64, dim3(16,8,3), dim3(256), 0, stream, hn16, wqkvT, qkv2);
    hipLaunchKernelGGL(k_att2fc, dim3(256), dim3(512), 0, stream,
                       qkv2, fcgT, mha_fc_b, mha_gate_b, hn16, hx, maskb, hx_out);
}